// Round 1
// baseline (202.494 us; speedup 1.0000x reference)
//
#include <hip/hip_runtime.h>
#include <math.h>

// Problem constants
#define B_SZ   512
#define L_SEQ  30
#define F_DIM  64
#define N_LEAD 500
#define MAXLAG 10
#define H_DIM  64
#define NROWS  5000          // N_LEAD * MAXLAG
#define TOPK   5

// Output layout (flat float32):
// pred [512] | top_k_indices [512*5*2] | top_k_scores [512*5] | attn [512*5000]
#define OFF_IDX   512
#define OFF_SCORE 5632
#define OFF_ATTN  8192

// ---------------------------------------------------------------------------
// Kernel A: LSTM over 30 steps + query = h@W_Q^T + kq = query@W_K  -> kq[B,64]
// One block per batch element; 256 threads = one per gate row.
// ---------------------------------------------------------------------------
__global__ __launch_bounds__(256) void lstm_kq_kernel(
    const float* __restrict__ x,      // [B,30,64]
    const float* __restrict__ W_ih,   // [256,64]
    const float* __restrict__ W_hh,   // [256,64]
    const float* __restrict__ b_ih,   // [256]
    const float* __restrict__ b_hh,   // [256]
    const float* __restrict__ W_Q,    // [64,64]
    const float* __restrict__ W_K,    // [64,64]
    float* __restrict__ kq)           // [B,64]
{
    __shared__ float xs[L_SEQ * F_DIM];   // 7.5 KB
    __shared__ float hs[H_DIM];
    __shared__ float gates[256];

    const int b = blockIdx.x;
    const int t = threadIdx.x;

    for (int i = t; i < L_SEQ * F_DIM; i += 256)
        xs[i] = x[b * L_SEQ * F_DIM + i];
    if (t < H_DIM) hs[t] = 0.f;

    // per-thread weight rows in registers (64+64 floats)
    float4 wih[16], whh[16];
    const float4* wihp = (const float4*)(W_ih + t * 64);
    const float4* whhp = (const float4*)(W_hh + t * 64);
#pragma unroll
    for (int k = 0; k < 16; ++k) { wih[k] = wihp[k]; whh[k] = whhp[k]; }
    const float bsum = b_ih[t] + b_hh[t];

    float c = 0.f;
    __syncthreads();

    for (int step = 0; step < L_SEQ; ++step) {
        float g = bsum;
        const float4* xv = (const float4*)(xs + step * F_DIM);
        const float4* hv = (const float4*)hs;
#pragma unroll
        for (int k = 0; k < 16; ++k) {
            float4 xk = xv[k], hk = hv[k];
            g += wih[k].x * xk.x + wih[k].y * xk.y + wih[k].z * xk.z + wih[k].w * xk.w;
            g += whh[k].x * hk.x + whh[k].y * hk.y + whh[k].z * hk.z + whh[k].w * hk.w;
        }
        gates[t] = g;
        __syncthreads();
        if (t < H_DIM) {
            float ig = 1.f / (1.f + expf(-gates[t]));
            float fg = 1.f / (1.f + expf(-gates[t + 64]));
            float gg = tanhf(gates[t + 128]);
            float og = 1.f / (1.f + expf(-gates[t + 192]));
            c = fg * c + ig * gg;
            hs[t] = og * tanhf(c);
        }
        __syncthreads();
    }

    // query[j] = dot(W_Q[j,:], h_last)   (reuse gates[] as query storage)
    if (t < H_DIM) {
        float q = 0.f;
        const float4* wq = (const float4*)(W_Q + t * 64);
        const float4* hv = (const float4*)hs;
#pragma unroll
        for (int k = 0; k < 16; ++k) {
            float4 w = wq[k], h4 = hv[k];
            q += w.x * h4.x + w.y * h4.y + w.z * h4.z + w.w * h4.w;
        }
        gates[t] = q;
    }
    __syncthreads();
    // kq[f] = sum_h query[h] * W_K[h,f]  (coalesced over f)
    if (t < F_DIM) {
        float acc = 0.f;
        for (int h = 0; h < H_DIM; ++h)
            acc += gates[h] * W_K[h * F_DIM + t];
        kq[b * F_DIM + t] = acc;
    }
}

// ---------------------------------------------------------------------------
// Kernel B: attn[b,row] = dot(raw[b,row,:], kq[b,:]) * (1/8)
// 16 lanes cooperate per row (float4 each), shfl_xor reduce. Streams 655 MB.
// ---------------------------------------------------------------------------
#define CHUNKS 10
#define ROWS_PER_BLK 500
__global__ __launch_bounds__(256) void attn_kernel(
    const float4* __restrict__ raw,   // [B*5000*16] as float4
    const float* __restrict__ kq,     // [B,64]
    float* __restrict__ attn)         // [B*5000]
{
    const int b     = blockIdx.x / CHUNKS;
    const int chunk = blockIdx.x % CHUNKS;
    const int sub   = threadIdx.x & 15;   // 0..15 : position within row
    const int rg    = threadIdx.x >> 4;   // 0..15 : row group

    const float4 kqv = ((const float4*)(kq + b * 64))[sub];
    const int base   = chunk * ROWS_PER_BLK;
    const long rowb  = (long)b * NROWS;

    for (int it = 0; it < 8; ++it) {
#pragma unroll
        for (int j = 0; j < 4; ++j) {
            int row = base + it * 64 + j * 16 + rg;
            if (row < base + ROWS_PER_BLK) {
                float4 v = raw[(rowb + row) * 16 + sub];
                float s = v.x * kqv.x + v.y * kqv.y + v.z * kqv.z + v.w * kqv.w;
                s += __shfl_xor(s, 8);
                s += __shfl_xor(s, 4);
                s += __shfl_xor(s, 2);
                s += __shfl_xor(s, 1);
                if (sub == 0) attn[rowb + row] = s * 0.125f;
            }
        }
    }
}

// ---------------------------------------------------------------------------
// Kernel C: per-batch top-5 (jax tie semantics) + softmax + gather + MLP
// ---------------------------------------------------------------------------
__global__ __launch_bounds__(256) void topk_mlp_kernel(
    const float* __restrict__ attn,   // [B*5000] already scaled
    const float* __restrict__ raw,    // [B*5000*64]
    const float* __restrict__ Wp1, const float* __restrict__ bp1,
    const float* __restrict__ Wp2, const float* __restrict__ bp2,
    const float* __restrict__ Wp3, const float* __restrict__ bp3,
    float* __restrict__ out)
{
    __shared__ float av[NROWS];       // 20 KB
    __shared__ float redv[4];
    __shared__ int   redi[4];
    __shared__ float topv[TOPK];
    __shared__ int   topi[TOPK];
    __shared__ float sc[TOPK];
    __shared__ float wsum[64];
    __shared__ float h1[64];
    __shared__ float h2[32];

    const int b = blockIdx.x, t = threadIdx.x;

    for (int i = t; i < NROWS; i += 256) av[i] = attn[(long)b * NROWS + i];
    __syncthreads();

    // 5 sequential argmax passes; ties -> lowest index (lax.top_k semantics)
    for (int p = 0; p < TOPK; ++p) {
        float bv = -INFINITY; int bi = 0x7fffffff;
        for (int i = t; i < NROWS; i += 256) {
            float v = av[i];
            if (v > bv || (v == bv && i < bi)) { bv = v; bi = i; }
        }
#pragma unroll
        for (int m = 32; m >= 1; m >>= 1) {
            float ov = __shfl_xor(bv, m);
            int   oi = __shfl_xor(bi, m);
            if (ov > bv || (ov == bv && oi < bi)) { bv = ov; bi = oi; }
        }
        if ((t & 63) == 0) { redv[t >> 6] = bv; redi[t >> 6] = bi; }
        __syncthreads();
        if (t == 0) {
            for (int w = 1; w < 4; ++w)
                if (redv[w] > bv || (redv[w] == bv && redi[w] < bi)) { bv = redv[w]; bi = redi[w]; }
            topv[p] = bv; topi[p] = bi;
            av[bi] = -INFINITY;
        }
        __syncthreads();
    }

    if (t == 0) {
        float mx = topv[0];   // pass 0 is the global max
        float e[TOPK], s = 0.f;
        for (int k = 0; k < TOPK; ++k) { e[k] = expf(topv[k] - mx); s += e[k]; }
        float inv = 1.f / s;
        for (int k = 0; k < TOPK; ++k) {
            sc[k] = e[k] * inv;
            out[OFF_IDX + b * 10 + 2 * k]     = (float)(topi[k] / MAXLAG);
            out[OFF_IDX + b * 10 + 2 * k + 1] = (float)(topi[k] % MAXLAG);
            out[OFF_SCORE + b * TOPK + k]     = sc[k];
        }
    }
    __syncthreads();

    // weighted = sum_k score_k * raw[b, topi_k, :]
    if (t < 64) {
        float acc = 0.f;
        for (int k = 0; k < TOPK; ++k)
            acc += sc[k] * raw[((long)b * NROWS + topi[k]) * 64 + t];
        wsum[t] = acc;
    }
    __syncthreads();
    if (t < 64) {
        float a = bp1[t];
        for (int f = 0; f < 64; ++f) a += Wp1[t * 64 + f] * wsum[f];
        h1[t] = fmaxf(a, 0.f);
    }
    __syncthreads();
    if (t < 32) {
        float a = bp2[t];
        for (int f = 0; f < 64; ++f) a += Wp2[t * 64 + f] * h1[f];
        h2[t] = fmaxf(a, 0.f);
    }
    __syncthreads();
    if (t == 0) {
        float a = bp3[0];
        for (int f = 0; f < 32; ++f) a += Wp3[f] * h2[f];
        out[b] = a;
    }
}

// ---------------------------------------------------------------------------
extern "C" void kernel_launch(void* const* d_in, const int* in_sizes, int n_in,
                              void* d_out, int out_size, void* d_ws, size_t ws_size,
                              hipStream_t stream) {
    const float* target = (const float*)d_in[0];
    const float* raw    = (const float*)d_in[1];
    const float* W_ih   = (const float*)d_in[2];
    const float* W_hh   = (const float*)d_in[3];
    const float* b_ih   = (const float*)d_in[4];
    const float* b_hh   = (const float*)d_in[5];
    const float* W_Q    = (const float*)d_in[6];
    const float* W_K    = (const float*)d_in[7];
    const float* Wp1    = (const float*)d_in[8];
    const float* bp1    = (const float*)d_in[9];
    const float* Wp2    = (const float*)d_in[10];
    const float* bp2    = (const float*)d_in[11];
    const float* Wp3    = (const float*)d_in[12];
    const float* bp3    = (const float*)d_in[13];

    float* out      = (float*)d_out;
    float* kq       = (float*)d_ws;                 // [512*64] floats
    float* attn_out = out + OFF_ATTN;

    hipLaunchKernelGGL(lstm_kq_kernel, dim3(B_SZ), dim3(256), 0, stream,
                       target, W_ih, W_hh, b_ih, b_hh, W_Q, W_K, kq);
    hipLaunchKernelGGL(attn_kernel, dim3(B_SZ * CHUNKS), dim3(256), 0, stream,
                       (const float4*)raw, kq, attn_out);
    hipLaunchKernelGGL(topk_mlp_kernel, dim3(B_SZ), dim3(256), 0, stream,
                       attn_out, raw, Wp1, bp1, Wp2, bp2, Wp3, bp3, out);
}